// Round 2
// baseline (265.307 us; speedup 1.0000x reference)
//
#include <hip/hip_runtime.h>

#define BB 32
#define TT 512
#define DD 768
#define ROWS_PER_BLOCK 8
#define VEC_PER_ROW (DD / 4)   // 192 float4 per row

// Kernel 1: reps = floor(max(dur,0)+0.5); inclusive cumsum per batch.
__global__ __launch_bounds__(TT) void lr_scan_kernel(
    const float* __restrict__ dur, int* __restrict__ cum) {
    __shared__ int s[TT];
    const int b = blockIdx.x;
    const int t = threadIdx.x;
    float d = dur[b * TT + t];
    d = fmaxf(d, 0.0f);
    s[t] = (int)floorf(d + 0.5f);
    __syncthreads();
    // Hillis-Steele inclusive scan over 512 elements (9 steps: offsets 1..256)
    #pragma unroll
    for (int off = 1; off < TT; off <<= 1) {
        int v = (t >= off) ? s[t - off] : 0;
        __syncthreads();
        s[t] += v;
        __syncthreads();
    }
    cum[b * TT + t] = s[t];
}

// Kernel 2: for each output row (b,pos): idx = upper_bound(cum[b], pos),
// copy x[b, idx, :] (768 fp32 = 192 float4, one per thread), zero if masked.
__global__ __launch_bounds__(VEC_PER_ROW) void lr_gather_kernel(
    const float* __restrict__ x, const int* __restrict__ cum,
    float* __restrict__ out, int t_out) {
    __shared__ int scum[TT];
    const int b = blockIdx.y;
    const int tid = threadIdx.x;

    // stage cum[b] into LDS (2 KB)
    for (int i = tid; i < TT; i += VEC_PER_ROW) scum[i] = cum[b * TT + i];
    __syncthreads();

    const int total = scum[TT - 1];
    const int row0 = blockIdx.x * ROWS_PER_BLOCK;

    const float4* xb = (const float4*)(x + (size_t)b * TT * DD);
    float4* ob = (float4*)(out + (size_t)b * (size_t)t_out * DD);

    #pragma unroll
    for (int r = 0; r < ROWS_PER_BLOCK; ++r) {
        const int pos = row0 + r;
        if (pos >= t_out) break;
        float4 v;
        if (pos >= total) {
            v = make_float4(0.f, 0.f, 0.f, 0.f);
        } else {
            // upper_bound over scum: first index with scum[idx] > pos.
            // Wave-uniform (all lanes same pos) -> LDS broadcast, no divergence.
            // NOTE: must run until lo==hi (10 steps for 512) — a fixed 9-step
            // loop leaves a width-1 interval and can return ans-1 (round-1 bug).
            int lo = 0, hi = TT;
            while (lo < hi) {
                int mid = (lo + hi) >> 1;
                if (scum[mid] <= pos) lo = mid + 1; else hi = mid;
            }
            int idx = lo < (TT - 1) ? lo : (TT - 1);
            v = xb[(size_t)idx * VEC_PER_ROW + tid];
        }
        ob[(size_t)pos * VEC_PER_ROW + tid] = v;
    }
}

extern "C" void kernel_launch(void* const* d_in, const int* in_sizes, int n_in,
                              void* d_out, int out_size, void* d_ws, size_t ws_size,
                              hipStream_t stream) {
    const float* x   = (const float*)d_in[0];
    const float* dur = (const float*)d_in[1];
    float* out = (float*)d_out;
    int* cum = (int*)d_ws;   // B*T ints = 64 KB

    const int t_out = out_size / (BB * DD);

    lr_scan_kernel<<<BB, TT, 0, stream>>>(dur, cum);

    dim3 grid((t_out + ROWS_PER_BLOCK - 1) / ROWS_PER_BLOCK, BB);
    lr_gather_kernel<<<grid, VEC_PER_ROW, 0, stream>>>(x, cum, out, t_out);
}

// Round 3
// 261.707 us; speedup vs baseline: 1.0138x; 1.0138x over previous
//
#include <hip/hip_runtime.h>

#define BB 32
#define TT 512
#define DD 768
#define VEC_PER_ROW (DD / 4)    // 192 float4 per row
#define TOK_PER_BLOCK 8         // source tokens per scatter block
#define TAIL_ROWS 8             // output rows per tail-zero block

// Kernel 1: reps = floor(max(dur,0)+0.5); inclusive cumsum per batch.
__global__ __launch_bounds__(TT) void lr_scan_kernel(
    const float* __restrict__ dur, int* __restrict__ cum) {
    __shared__ int s[TT];
    const int b = blockIdx.x;
    const int t = threadIdx.x;
    float d = dur[b * TT + t];
    d = fmaxf(d, 0.0f);
    s[t] = (int)floorf(d + 0.5f);
    __syncthreads();
    #pragma unroll
    for (int off = 1; off < TT; off <<= 1) {
        int v = (t >= off) ? s[t - off] : 0;
        __syncthreads();
        s[t] += v;
        __syncthreads();
    }
    cum[b * TT + t] = s[t];
}

// Kernel 2 (source-centric): each block owns TOK_PER_BLOCK source tokens of
// one batch. Each x row (192 float4, one per lane) is loaded from HBM exactly
// once into registers, then stored reps times to consecutive output rows
// [cum[t-1], cum[t]). Inner loop bounds are block-uniform -> no divergence.
__global__ __launch_bounds__(VEC_PER_ROW) void lr_scatter_kernel(
    const float* __restrict__ x, const int* __restrict__ cum,
    float* __restrict__ out, int t_out) {
    __shared__ int scum[TT];
    const int b = blockIdx.y;
    const int tid = threadIdx.x;

    for (int i = tid; i < TT; i += VEC_PER_ROW) scum[i] = cum[b * TT + i];
    __syncthreads();

    const int s0 = blockIdx.x * TOK_PER_BLOCK;
    const float4* xb = (const float4*)(x + (size_t)b * TT * DD);
    float4* ob = (float4*)(out + (size_t)b * (size_t)t_out * DD);

    #pragma unroll
    for (int k = 0; k < TOK_PER_BLOCK; ++k) {
        const int t = s0 + k;
        const int start = (t == 0) ? 0 : scum[t - 1];
        const int end = scum[t];
        if (end > start) {                     // block-uniform branch
            const float4 v = xb[(size_t)t * VEC_PER_ROW + tid];
            for (int p = start; p < end; ++p)  // 1..8 iters, block-uniform
                ob[(size_t)p * VEC_PER_ROW + tid] = v;
        }
    }
}

// Kernel 3: zero the masked tail rows [total_b, t_out). Blocks entirely below
// total exit after one cached scalar load.
__global__ __launch_bounds__(VEC_PER_ROW) void lr_zero_tail_kernel(
    const int* __restrict__ cum, float* __restrict__ out, int t_out) {
    const int b = blockIdx.y;
    const int total = cum[b * TT + (TT - 1)];
    const int row0 = blockIdx.x * TAIL_ROWS;
    if (row0 + TAIL_ROWS <= total) return;     // fully covered by scatter

    const int tid = threadIdx.x;
    float4* ob = (float4*)(out + (size_t)b * (size_t)t_out * DD);
    const float4 z = make_float4(0.f, 0.f, 0.f, 0.f);
    #pragma unroll
    for (int r = 0; r < TAIL_ROWS; ++r) {
        const int pos = row0 + r;
        if (pos >= total && pos < t_out)
            ob[(size_t)pos * VEC_PER_ROW + tid] = z;
    }
}

extern "C" void kernel_launch(void* const* d_in, const int* in_sizes, int n_in,
                              void* d_out, int out_size, void* d_ws, size_t ws_size,
                              hipStream_t stream) {
    const float* x   = (const float*)d_in[0];
    const float* dur = (const float*)d_in[1];
    float* out = (float*)d_out;
    int* cum = (int*)d_ws;   // B*T ints = 64 KB

    const int t_out = out_size / (BB * DD);

    lr_scan_kernel<<<BB, TT, 0, stream>>>(dur, cum);

    dim3 sgrid(TT / TOK_PER_BLOCK, BB);        // 64 x 32 blocks
    lr_scatter_kernel<<<sgrid, VEC_PER_ROW, 0, stream>>>(x, cum, out, t_out);

    dim3 zgrid((t_out + TAIL_ROWS - 1) / TAIL_ROWS, BB);
    lr_zero_tail_kernel<<<zgrid, VEC_PER_ROW, 0, stream>>>(cum, out, t_out);
}

// Round 5
// 255.730 us; speedup vs baseline: 1.0375x; 1.0234x over previous
//
#include <hip/hip_runtime.h>

#define BB 32
#define TT 512
#define DD 768
#define VEC_PER_ROW (DD / 4)    // 192 float4 per row
#define TOK_PER_BLOCK 8         // source tokens per scatter block
#define BLOCKS_PER_BATCH (TT / TOK_PER_BLOCK)   // 64

// Native clang vector type — required by __builtin_nontemporal_store
// (HIP_vector_type float4 is a struct, rejected).
typedef float f4 __attribute__((ext_vector_type(4)));

// Kernel 1: reps = floor(max(dur,0)+0.5); inclusive cumsum per batch.
__global__ __launch_bounds__(TT) void lr_scan_kernel(
    const float* __restrict__ dur, int* __restrict__ cum) {
    __shared__ int s[TT];
    const int b = blockIdx.x;
    const int t = threadIdx.x;
    float d = dur[b * TT + t];
    d = fmaxf(d, 0.0f);
    s[t] = (int)floorf(d + 0.5f);
    __syncthreads();
    #pragma unroll
    for (int off = 1; off < TT; off <<= 1) {
        int v = (t >= off) ? s[t - off] : 0;
        __syncthreads();
        s[t] += v;
        __syncthreads();
    }
    cum[b * TT + t] = s[t];
}

// Kernel 2 (fused scatter + tail-zero): each block owns TOK_PER_BLOCK source
// tokens of one batch. Each x row (192 f4, one per lane) is read exactly
// once (L3-resident anyway), stored reps times to consecutive output rows —
// non-temporal (write-once stream, skip L2 allocation). Then the masked tail
// [total, t_out) is zeroed cooperatively by the batch's 64 blocks.
__global__ __launch_bounds__(VEC_PER_ROW) void lr_scatter_kernel(
    const float* __restrict__ x, const int* __restrict__ cum,
    float* __restrict__ out, int t_out) {
    __shared__ int scum[TT];
    const int b = blockIdx.y;
    const int tid = threadIdx.x;

    for (int i = tid; i < TT; i += VEC_PER_ROW) scum[i] = cum[b * TT + i];
    __syncthreads();

    const int s0 = blockIdx.x * TOK_PER_BLOCK;
    const f4* xb = (const f4*)(x + (size_t)b * TT * DD);
    f4* ob = (f4*)(out + (size_t)b * (size_t)t_out * DD);

    #pragma unroll
    for (int k = 0; k < TOK_PER_BLOCK; ++k) {
        const int t = s0 + k;
        const int start = (t == 0) ? 0 : scum[t - 1];
        const int end = scum[t];
        if (end > start) {                     // block-uniform branch
            const f4 v = xb[(size_t)t * VEC_PER_ROW + tid];
            for (int p = start; p < end; ++p)  // 1..8 iters, block-uniform
                __builtin_nontemporal_store(v, &ob[(size_t)p * VEC_PER_ROW + tid]);
        }
    }

    // Tail zero: rows [total, t_out) striped across the batch's 64 blocks.
    const int total = scum[TT - 1];
    const f4 z = (f4)(0.0f);
    for (int pos = total + blockIdx.x; pos < t_out; pos += BLOCKS_PER_BATCH)
        __builtin_nontemporal_store(z, &ob[(size_t)pos * VEC_PER_ROW + tid]);
}

extern "C" void kernel_launch(void* const* d_in, const int* in_sizes, int n_in,
                              void* d_out, int out_size, void* d_ws, size_t ws_size,
                              hipStream_t stream) {
    const float* x   = (const float*)d_in[0];
    const float* dur = (const float*)d_in[1];
    float* out = (float*)d_out;
    int* cum = (int*)d_ws;   // B*T ints = 64 KB

    const int t_out = out_size / (BB * DD);

    lr_scan_kernel<<<BB, TT, 0, stream>>>(dur, cum);

    dim3 sgrid(BLOCKS_PER_BATCH, BB);          // 64 x 32 blocks
    lr_scatter_kernel<<<sgrid, VEC_PER_ROW, 0, stream>>>(x, cum, out, t_out);
}

// Round 6
// 254.103 us; speedup vs baseline: 1.0441x; 1.0064x over previous
//
#include <hip/hip_runtime.h>

#define BB 32
#define TT 512
#define DD 768
#define NTHREADS 192            // = DD/4 float4 lanes per row
#define TOK_PER_BLOCK 8         // source tokens per block
#define BLOCKS_PER_BATCH (TT / TOK_PER_BLOCK)   // 64

// Native clang vector type — required by __builtin_nontemporal_store
// (HIP_vector_type float4 is a struct, rejected).
typedef float f4 __attribute__((ext_vector_type(4)));

// Single fused kernel. Each block:
//  1. Redundantly computes its batch's reps = round(max(dur,0)) and the
//     512-wide inclusive scan in LDS (cheap: 2 KB dur read is L2/L3-hit,
//     ~18 barriers of trivial LDS work). Removes the separate scan kernel,
//     its launch latency, and the d_ws round-trip.
//  2. Scatters its TOK_PER_BLOCK source rows: each x row (192 f4, one per
//     lane) read exactly once, stored reps times to consecutive output rows
//     with non-temporal stores (write-once stream).
//  3. Cooperatively zeroes the masked tail [total, t_out) striped across the
//     batch's 64 blocks.
__global__ __launch_bounds__(NTHREADS) void lr_fused_kernel(
    const float* __restrict__ x, const float* __restrict__ dur,
    float* __restrict__ out, int t_out) {
    __shared__ int scum[TT];
    const int b = blockIdx.y;
    const int tid = threadIdx.x;

    // reps into LDS
    for (int i = tid; i < TT; i += NTHREADS) {
        float d = fmaxf(dur[b * TT + i], 0.0f);
        scum[i] = (int)floorf(d + 0.5f);
    }
    __syncthreads();

    // Hillis-Steele inclusive scan over 512 elements with 192 threads
    // (lanes own indices tid, tid+192, tid+384; read-all / barrier / write-all
    // per step keeps it race-free).
    #pragma unroll
    for (int off = 1; off < TT; off <<= 1) {
        const int i0 = tid, i1 = tid + NTHREADS, i2 = tid + 2 * NTHREADS;
        int v0 = (i0 >= off) ? scum[i0 - off] : 0;
        int v1 = (i1 >= off) ? scum[i1 - off] : 0;
        int v2 = (i2 < TT && i2 >= off) ? scum[i2 - off] : 0;
        __syncthreads();
        scum[i0] += v0;
        scum[i1] += v1;
        if (i2 < TT) scum[i2] += v2;
        __syncthreads();
    }

    // Scatter this block's 8 source tokens.
    const int s0 = blockIdx.x * TOK_PER_BLOCK;
    const f4* xb = (const f4*)(x + (size_t)b * TT * DD);
    f4* ob = (f4*)(out + (size_t)b * (size_t)t_out * DD);

    #pragma unroll
    for (int k = 0; k < TOK_PER_BLOCK; ++k) {
        const int t = s0 + k;
        const int start = (t == 0) ? 0 : scum[t - 1];
        const int end = scum[t];
        if (end > start) {                     // block-uniform branch
            const f4 v = xb[(size_t)t * NTHREADS + tid];
            for (int p = start; p < end; ++p)  // 0..8 iters, block-uniform
                __builtin_nontemporal_store(v, &ob[(size_t)p * NTHREADS + tid]);
        }
    }

    // Tail zero: rows [total, t_out) striped across the batch's 64 blocks.
    const int total = scum[TT - 1];
    const f4 z = (f4)(0.0f);
    for (int pos = total + blockIdx.x; pos < t_out; pos += BLOCKS_PER_BATCH)
        __builtin_nontemporal_store(z, &ob[(size_t)pos * NTHREADS + tid]);
}

extern "C" void kernel_launch(void* const* d_in, const int* in_sizes, int n_in,
                              void* d_out, int out_size, void* d_ws, size_t ws_size,
                              hipStream_t stream) {
    const float* x   = (const float*)d_in[0];
    const float* dur = (const float*)d_in[1];
    float* out = (float*)d_out;
    (void)d_ws; (void)ws_size;

    const int t_out = out_size / (BB * DD);

    dim3 grid(BLOCKS_PER_BATCH, BB);           // 64 x 32 blocks
    lr_fused_kernel<<<grid, NTHREADS, 0, stream>>>(x, dur, out, t_out);
}